// Round 3
// baseline (8155.850 us; speedup 1.0000x reference)
//
#include <hip/hip_runtime.h>
#include <hip/hip_bf16.h>
#include <stdint.h>

// Problem dims (fixed)
#define Bn   2
#define Tn   1024
#define NTOK 2048      // B*T
#define Vn   32000
#define En   512
#define Hn   768
#define H3   2304      // 3*H
#define Mn   256
#define Rn   64
#define Gn   16

typedef __attribute__((ext_vector_type(8))) short short8;
typedef __attribute__((ext_vector_type(4))) float f32x4;

__device__ __forceinline__ float sigmoidf_(float x) { return 1.f / (1.f + __expf(-x)); }

__device__ __forceinline__ unsigned short f2bf(float x) {
    union { float f; unsigned u; } v; v.f = x;
    unsigned r = v.u + 0x7fffu + ((v.u >> 16) & 1u);   // RNE
    return (unsigned short)(r >> 16);
}

// ---------------------------------------------------------------------------
// fp32 GEMM for small N: C = act(A @ B^T + bias). 64x64 tile, BK=16.
// ACT: 0=none, 1=sigmoid
// ---------------------------------------------------------------------------
template<int ACT>
__global__ __launch_bounds__(256) void gemm_nt_f32(
    const float* __restrict__ A, const float* __restrict__ B,
    float* __restrict__ C, const float* __restrict__ bias,
    int M, int N, int K)
{
    __shared__ float As[16][68];
    __shared__ float Bs[16][68];
    const int m0 = blockIdx.y * 64, n0 = blockIdx.x * 64;
    const int tid = threadIdx.x;
    const int tx = tid & 15, ty = tid >> 4;
    float acc[4][4] = {};
    for (int k0 = 0; k0 < K; k0 += 16) {
        #pragma unroll
        for (int i = 0; i < 4; i++) {
            int idx = tid + i * 256;
            int r = idx >> 4, c = idx & 15;
            int gm = m0 + r;
            As[c][r] = (gm < M) ? A[(long)gm * K + k0 + c] : 0.f;
            int gn = n0 + r;
            Bs[c][r] = (gn < N) ? B[(long)gn * K + k0 + c] : 0.f;
        }
        __syncthreads();
        #pragma unroll
        for (int kk = 0; kk < 16; kk++) {
            float4 a4 = *(const float4*)&As[kk][ty * 4];
            float4 b4 = *(const float4*)&Bs[kk][tx * 4];
            float a[4] = {a4.x, a4.y, a4.z, a4.w};
            float b[4] = {b4.x, b4.y, b4.z, b4.w};
            #pragma unroll
            for (int i = 0; i < 4; i++)
                #pragma unroll
                for (int j = 0; j < 4; j++) acc[i][j] += a[i] * b[j];
        }
        __syncthreads();
    }
    #pragma unroll
    for (int i = 0; i < 4; i++) {
        int gm = m0 + ty * 4 + i; if (gm >= M) continue;
        #pragma unroll
        for (int j = 0; j < 4; j++) {
            int gn = n0 + tx * 4 + j; if (gn >= N) continue;
            float v = acc[i][j] + (bias ? bias[gn] : 0.f);
            if (ACT == 1) v = sigmoidf_(v);
            C[(long)gm * N + gn] = v;
        }
    }
}

// ---------------------------------------------------------------------------
// bf16 MFMA GEMM: C = act(A_bf @ B_bf^T + bias). 128x128 tile, BK=32,
// 4 waves (2x2), 16x16x32 bf16 MFMA, global_load_lds width-16 staging.
// All of M, N multiples of 128 per launch config; K multiple of 32.
// Optional row-gather on A. Batched via blockIdx.z (element strides).
// ACT: 0=none, 2=relu^2. OBF: 0=f32 out, 1=bf16 out.
// ---------------------------------------------------------------------------
typedef const __attribute__((address_space(1))) void* as1cv_t;
typedef __attribute__((address_space(3))) void* as3v_t;
__device__ __forceinline__ void gload_lds16(const void* g, void* l) {
    __builtin_amdgcn_global_load_lds((as1cv_t)g, (as3v_t)l, 16, 0, 0);
}

template<int ACT, int OBF>
__global__ __launch_bounds__(256) void gemm_bf16_mfma(
    const unsigned short* __restrict__ A, const unsigned short* __restrict__ B,
    const float* __restrict__ bias, void* __restrict__ Cout,
    int N, int K, long sA, long sB, long sC,
    const int* __restrict__ gatherA)
{
    A += blockIdx.z * sA; B += blockIdx.z * sB;
    __shared__ __align__(16) unsigned short As[128 * 32];
    __shared__ __align__(16) unsigned short Bs[128 * 32];
    const int n0 = blockIdx.x * 128;
    const int m0 = blockIdx.y * 128;
    const int tid = threadIdx.x;
    const int lane = tid & 63, wv = tid >> 6;
    const int wr = wv >> 1, wc = wv & 1;
    f32x4 zero4 = {0.f, 0.f, 0.f, 0.f};
    f32x4 acc[4][4];
    #pragma unroll
    for (int i = 0; i < 4; i++)
        #pragma unroll
        for (int j = 0; j < 4; j++) acc[i][j] = zero4;

    const int lrow = lane & 15, lko = (lane >> 4) * 8;
    const int cb = (lane * 16) & 63;          // byte offset within 64B tile row
    int rowsA[2], rowsB[2];
    #pragma unroll
    for (int i = 0; i < 2; i++) {
        int p = i * 4096 + wv * 1024 + lane * 16;
        int row = p >> 6;
        rowsA[i] = gatherA ? gatherA[m0 + row] : (m0 + row);
        rowsB[i] = n0 + row;
    }

    for (int k0 = 0; k0 < K; k0 += 32) {
        __syncthreads();
        #pragma unroll
        for (int i = 0; i < 2; i++) {
            int base = i * 4096 + wv * 1024;  // wave-uniform LDS byte offset
            gload_lds16((const char*)A + ((long)rowsA[i] * K + k0) * 2 + cb, (char*)As + base);
            gload_lds16((const char*)B + ((long)rowsB[i] * K + k0) * 2 + cb, (char*)Bs + base);
        }
        __syncthreads();
        short8 af[4], bfr[4];
        #pragma unroll
        for (int m = 0; m < 4; m++)
            af[m] = *(const short8*)((const char*)As + (wr * 64 + m * 16 + lrow) * 64 + lko * 2);
        #pragma unroll
        for (int n = 0; n < 4; n++)
            bfr[n] = *(const short8*)((const char*)Bs + (wc * 64 + n * 16 + lrow) * 64 + lko * 2);
        #pragma unroll
        for (int m = 0; m < 4; m++)
            #pragma unroll
            for (int n = 0; n < 4; n++)
                acc[m][n] = __builtin_amdgcn_mfma_f32_16x16x32_bf16(af[m], bfr[n], acc[m][n], 0, 0, 0);
    }
    const int orow = (lane >> 4) * 4, ocol = lane & 15;
    float* Cf = (float*)Cout + blockIdx.z * sC;
    unsigned short* Cb = (unsigned short*)Cout + blockIdx.z * sC;
    #pragma unroll
    for (int m = 0; m < 4; m++) {
        #pragma unroll
        for (int n = 0; n < 4; n++) {
            int col = n0 + wc * 64 + n * 16 + ocol;
            float bv = bias ? bias[col] : 0.f;
            int rbase = m0 + wr * 64 + m * 16 + orow;
            #pragma unroll
            for (int r2 = 0; r2 < 4; r2++) {
                float v = acc[m][n][r2] + bv;
                if (ACT == 2) { v = fmaxf(v, 0.f); v = v * v; }
                if (OBF) Cb[(long)(rbase + r2) * N + col] = f2bf(v);
                else     Cf[(long)(rbase + r2) * N + col] = v;
            }
        }
    }
}

// ---------------------------------------------------------------------------
// GRU scan v3: barrier-free dataflow + per-wave epoch flags.
// 128 blocks x 64 threads. Wave w owns j in [6w,6w+6).
// Producers: store 12 h dwords (relaxed agent) -> s_waitcnt vmcnt(0)
// (wave-wide release point) -> lane0 stores flags[w]=t+1.
// Consumers: spin on ONE 8B flag load per lane (128 flags total), then read
// h data once (8B loads, NaN-sentinel backstop loop).
// ---------------------------------------------------------------------------
#define GRU_SENT 0xFFFFFFFFu
__global__ __launch_bounds__(64, 1) void gru_scan3_k(
    const float* __restrict__ xi, const float* __restrict__ Whh,
    const float* __restrict__ bhh, float* __restrict__ states,
    float* __restrict__ hseq, unsigned* __restrict__ flags)
{
    const int w = blockIdx.x;        // 0..127
    const int lane = threadIdx.x;    // 0..63
    const int jb = w * 6;

    float wreg[3][6][12];
    #pragma unroll
    for (int g = 0; g < 3; g++)
        #pragma unroll
        for (int jo = 0; jo < 6; jo++) {
            const float* wp = Whh + (long)(g * Hn + jb + jo) * Hn + lane * 12;
            #pragma unroll
            for (int c = 0; c < 12; c += 4) {
                float4 v = *(const float4*)(wp + c);
                wreg[g][jo][c + 0] = v.x; wreg[g][jo][c + 1] = v.y;
                wreg[g][jo][c + 2] = v.z; wreg[g][jo][c + 3] = v.w;
            }
        }

    const bool own = (lane < 12);
    const int jo_own = lane >> 1, b_own = lane & 1;
    const int j_own = jb + jo_own;
    float bh0 = 0.f, bh1 = 0.f, bh2 = 0.f;
    if (own) { bh0 = bhh[j_own]; bh1 = bhh[Hn + j_own]; bh2 = bhh[2 * Hn + j_own]; }
    float hreg = 0.f;

    const uint* __restrict__ hsq = (const uint*)hseq;
    uint* __restrict__ hsqw = (uint*)hseq;
    const unsigned long long* __restrict__ fl8 = (const unsigned long long*)flags;

    for (int t = 0; t < Tn; t++) {
        // xi prefetch (independent of h availability; overlaps the flag spin)
        float xg0 = 0.f, xg1 = 0.f, xg2 = 0.f;
        if (own) {
            const float* xp = xi + ((long)b_own * Tn + t) * H3 + j_own;
            xg0 = xp[0]; xg1 = xp[Hn]; xg2 = xp[2 * Hn];
        }

        // spin on 2 epoch flags per lane (all 128 flags across the wave)
        {
            const unsigned thr = (unsigned)t;
            unsigned long long fv;
            do {
                fv = __hip_atomic_load(fl8 + lane, __ATOMIC_RELAXED, __HIP_MEMORY_SCOPE_AGENT);
            } while ((unsigned)fv < thr || (unsigned)(fv >> 32) < thr);
        }

        // read this lane's 24 h dwords (sentinel backstop; normally 1 pass)
        const uint* hp = hsq + (long)t * 2 * Hn + lane * 12;
        uint hu[24];
        bool ready;
        do {
            #pragma unroll
            for (int b = 0; b < 2; b++)
                #pragma unroll
                for (int c3 = 0; c3 < 6; c3++) {
                    unsigned long long u8 = __hip_atomic_load(
                        (const unsigned long long*)(hp + b * Hn) + c3,
                        __ATOMIC_RELAXED, __HIP_MEMORY_SCOPE_AGENT);
                    hu[b * 12 + c3 * 2]     = (unsigned)u8;
                    hu[b * 12 + c3 * 2 + 1] = (unsigned)(u8 >> 32);
                }
            ready = true;
            #pragma unroll
            for (int i = 0; i < 24; i++) ready = ready && (hu[i] != GRU_SENT);
        } while (!ready);
        float hv[2][12];
        #pragma unroll
        for (int b = 0; b < 2; b++)
            #pragma unroll
            for (int c = 0; c < 12; c++) hv[b][c] = __uint_as_float(hu[b * 12 + c]);

        // dot products: 18 rows x 2 batches
        float acc[3][6][2];
        #pragma unroll
        for (int g = 0; g < 3; g++)
            #pragma unroll
            for (int jo = 0; jo < 6; jo++) {
                float s0 = 0.f, s1 = 0.f;
                #pragma unroll
                for (int c = 0; c < 12; c++) {
                    s0 += wreg[g][jo][c] * hv[0][c];
                    s1 += wreg[g][jo][c] * hv[1][c];
                }
                acc[g][jo][0] = s0; acc[g][jo][1] = s1;
            }

        // batch-folded butterfly
        float red[3][6];
        #pragma unroll
        for (int g = 0; g < 3; g++)
            #pragma unroll
            for (int jo = 0; jo < 6; jo++) {
                float keep = (lane & 1) ? acc[g][jo][1] : acc[g][jo][0];
                float send = (lane & 1) ? acc[g][jo][0] : acc[g][jo][1];
                red[g][jo] = keep + __shfl_xor(send, 1, 64);
            }
        #pragma unroll
        for (int m = 2; m < 64; m <<= 1)
            #pragma unroll
            for (int g = 0; g < 3; g++)
                #pragma unroll
                for (int jo = 0; jo < 6; jo++)
                    red[g][jo] += __shfl_xor(red[g][jo], m, 64);

        float hnew = 0.f;
        if (own) {
            float hr = 0.f, hz = 0.f, hn = 0.f;
            #pragma unroll
            for (int jo = 0; jo < 6; jo++)
                if (jo_own == jo) { hr = red[0][jo]; hz = red[1][jo]; hn = red[2][jo]; }
            hr += bh0; hz += bh1; hn += bh2;
            float rr = sigmoidf_(xg0 + hr);
            float zz = sigmoidf_(xg1 + hz);
            float nn = tanhf(xg2 + rr * hn);
            hnew = (1.f - zz) * nn + zz * hreg;
            hreg = hnew;
            __hip_atomic_store(hsqw + (long)(t + 1) * 2 * Hn + b_own * Hn + j_own,
                               __float_as_uint(hnew),
                               __ATOMIC_RELAXED, __HIP_MEMORY_SCOPE_AGENT);
        }
        // release point: wave's data stores complete, then publish epoch
        asm volatile("s_waitcnt vmcnt(0)" ::: "memory");
        if (lane == 0)
            __hip_atomic_store(flags + w, (unsigned)(t + 1),
                               __ATOMIC_RELAXED, __HIP_MEMORY_SCOPE_AGENT);
        // states store off the critical path
        if (own)
            states[((long)b_own * Tn + t) * Hn + j_own] = hnew;
    }
}

// ---------------------------------------------------------------------------
// Attention softmax (strictly causal, in-place over scores buffer).
// ---------------------------------------------------------------------------
__global__ __launch_bounds__(256) void attn_softmax_k(float* __restrict__ attn)
{
    const int t = blockIdx.x, b = blockIdx.y;
    float* row = attn + ((long)b * Tn + t) * Tn;
    const int tid = threadIdx.x;
    __shared__ float red[256];
    const float scale = 0.0625f;  // 1/sqrt(256)
    float mx = -3.4e38f;
    for (int s = tid; s < t; s += 256) mx = fmaxf(mx, row[s] * scale);
    red[tid] = mx; __syncthreads();
    for (int st = 128; st > 0; st >>= 1) { if (tid < st) red[tid] = fmaxf(red[tid], red[tid + st]); __syncthreads(); }
    mx = red[0]; __syncthreads();
    float sum = 0.f;
    for (int s = tid; s < t; s += 256) { float e = __expf(row[s] * scale - mx); row[s] = e; sum += e; }
    red[tid] = sum; __syncthreads();
    for (int st = 128; st > 0; st >>= 1) { if (tid < st) red[tid] += red[tid + st]; __syncthreads(); }
    sum = red[0];
    float inv = 1.f / fmaxf(sum, 1e-6f);
    for (int s = tid; s < t; s += 256) row[s] *= inv;
    for (int s = t + tid; s < Tn; s += 256) row[s] = 0.f;
}

// top-2 of 16 router logits + 2-way softmax (tie -> lowest index, matches top_k)
__global__ void route_topk_k(const float* __restrict__ rl, float* __restrict__ rw, int* __restrict__ ridx)
{
    int n = blockIdx.x * blockDim.x + threadIdx.x;
    if (n >= NTOK) return;
    const float* r = rl + (long)n * Gn;
    float v1 = -3.4e38f; int i1 = 0;
    #pragma unroll
    for (int g = 0; g < Gn; g++) { float v = r[g]; if (v > v1) { v1 = v; i1 = g; } }
    float v2 = -3.4e38f; int i2 = 0;
    #pragma unroll
    for (int g = 0; g < Gn; g++) { if (g == i1) continue; float v = r[g]; if (v > v2) { v2 = v; i2 = g; } }
    float e2 = __expf(v2 - v1);
    float s = 1.f + e2;
    rw[n * 2] = 1.f / s; rw[n * 2 + 1] = e2 / s;
    ridx[n * 2] = i1; ridx[n * 2 + 1] = i2;
}

// routed basis: out[n][r] += w_g * (inp[n,:] @ cw[g,:,r] + cb[g,r]) for g in top2(n)
__global__ __launch_bounds__(256) void routed_basis_k(
    const float* __restrict__ inp, const float* __restrict__ cw, const float* __restrict__ cb,
    const float* __restrict__ rw, const int* __restrict__ ridx,
    float* __restrict__ out, int D)
{
    const int g = blockIdx.x;
    const int t0 = blockIdx.y * 256;
    __shared__ float srow[Hn];
    __shared__ float part[4][64];
    const int r = threadIdx.x & 63, dq = threadIdx.x >> 6;
    const float* cwg = cw + (long)g * D * Rn;
    const int dlen = D >> 2;
    for (int ti = 0; ti < 256; ti++) {
        const int n = t0 + ti;
        float wt = 0.f;
        if (ridx[n * 2] == g) wt = rw[n * 2];
        else if (ridx[n * 2 + 1] == g) wt = rw[n * 2 + 1];
        if (wt == 0.f) continue;            // block-uniform
        __syncthreads();
        for (int d = threadIdx.x; d < D; d += 256) srow[d] = inp[(long)n * D + d];
        __syncthreads();
        float p = 0.f;
        const int dbeg = dq * dlen;
        for (int d = dbeg; d < dbeg + dlen; d++) p += srow[d] * cwg[(long)d * Rn + r];
        part[dq][r] = p;
        __syncthreads();
        if (dq == 0) {
            float sv = part[0][r] + part[1][r] + part[2][r] + part[3][r] + cb[g * Rn + r];
            atomicAdd(&out[(long)n * Rn + r], wt * sv);
        }
    }
}

__global__ void comb_k(const float* __restrict__ bb, const float* __restrict__ mb,
                       const float* __restrict__ bg, const float* __restrict__ bs_ptr,
                       float* __restrict__ comb)
{
    int i = blockIdx.x * 256 + threadIdx.x;
    if (i < NTOK * Rn) comb[i] = bb[i] + bs_ptr[0] * (bg[i] * mb[i]);
}

__global__ void ftotal_k(const float* __restrict__ bf, const float* __restrict__ dl,
                         unsigned short* __restrict__ outb)
{
    int i = blockIdx.x * 256 + threadIdx.x;
    if (i < NTOK * En) outb[i] = f2bf(bf[i] + dl[i]);
}

// generic f32 -> bf16 convert (n multiple of 4)
__global__ void convbf_k(const float* __restrict__ in, unsigned short* __restrict__ outb, long n)
{
    long i = (long)(blockIdx.x * 256 + threadIdx.x) * 4;
    for (; i < n; i += (long)gridDim.x * 256 * 4) {
        float4 v = *(const float4*)(in + i);
        ushort4 u;
        u.x = f2bf(v.x); u.y = f2bf(v.y); u.z = f2bf(v.z); u.w = f2bf(v.w);
        *(ushort4*)(outb + i) = u;
    }
}

// states (2,1024,768) f32 -> statesT (2,768,1024) bf16, tiled transpose
__global__ __launch_bounds__(256) void transbf_k(const float* __restrict__ st,
                                                 unsigned short* __restrict__ stT)
{
    __shared__ float tile[32][33];
    const int b = blockIdx.z;
    const int t0 = blockIdx.x * 32, h0 = blockIdx.y * 32;
    const int tx = threadIdx.x & 31, ty = threadIdx.x >> 5;   // 32x8
    #pragma unroll
    for (int r = ty; r < 32; r += 8)
        tile[r][tx] = st[((long)b * Tn + t0 + r) * Hn + h0 + tx];
    __syncthreads();
    #pragma unroll
    for (int r = ty; r < 32; r += 8)
        stT[((long)b * Hn + h0 + r) * Tn + t0 + tx] = f2bf(tile[tx][r]);
}

// copy mechanism: logits[b,t, ids[b,s]] += attn[b,t,s] * eg[b,t] * exact_scale
__global__ __launch_bounds__(256) void copy_scatter_k(
    float* __restrict__ logits, const float* __restrict__ attn,
    const float* __restrict__ eg, const int* __restrict__ ids,
    const float* __restrict__ esc)
{
    const int n = blockIdx.x;
    const int b = n >> 10, t = n & 1023;
    const float g = eg[n] * esc[0];
    const float* arow = attn + ((long)b * Tn + t) * Tn;
    float* lrow = logits + (long)n * Vn;
    const int* idrow = ids + b * Tn;
    for (int s = threadIdx.x; s < t; s += 256) {
        float a = arow[s];
        atomicAdd(lrow + idrow[s], a * g);
    }
}

// ---------------------------------------------------------------------------
extern "C" void kernel_launch(void* const* d_in, const int* in_sizes, int n_in,
                              void* d_out, int out_size, void* d_ws, size_t ws_size,
                              hipStream_t stream)
{
    const int*   ids      = (const int*)  d_in[0];
    const float* emb      = (const float*)d_in[1];
    const float* W_ih     = (const float*)d_in[2];
    const float* W_hh     = (const float*)d_in[3];
    const float* b_ih     = (const float*)d_in[4];
    const float* b_hh     = (const float*)d_in[5];
    const float* Wq       = (const float*)d_in[6];
    const float* bq       = (const float*)d_in[7];
    const float* Wk       = (const float*)d_in[8];
    const float* bk       = (const float*)d_in[9];
    const float* Wg       = (const float*)d_in[10];
    const float* bg       = (const float*)d_in[11];
    const float* Whf      = (const float*)d_in[12];
    const float* bhf      = (const float*)d_in[13];
    const float* Whp      = (const float*)d_in[14];
    const float* bhp      = (const float*)d_in[15];
    const float* Wr       = (const float*)d_in[16];
    const float* br       = (const float*)d_in[17];
    const float* base_cw  = (const float*)d_in[18];
    const float* base_cb  = (const float*)d_in[19];
    const float* mem_cw   = (const float*)d_in[20];
    const float* mem_cb   = (const float*)d_in[21];
    const float* Wbg      = (const float*)d_in[22];
    const float* bbg      = (const float*)d_in[23];
    const float* Wbu      = (const float*)d_in[24];
    const float* out_bias = (const float*)d_in[25];
    const float* esc      = (const float*)d_in[26];
    const float* bsc      = (const float*)d_in[27];
    float* logits = (float*)d_out;

    char* ws = (char*)d_ws;
    size_t off = 0;
    auto alloc = [&](size_t bytes) -> void* {
        void* p = ws + off; off = (off + bytes + 255) & ~(size_t)255; return p;
    };
    float* xi     = (float*)alloc((size_t)NTOK * H3 * 4);   // reused as head_bf after GRU
    unsigned short* head_bf = (unsigned short*)xi;          // 2048*2048*2B <= 2048*2304*4B
    float* states = (float*)alloc((size_t)NTOK * Hn * 4);
    float* hseq   = (float*)alloc((size_t)(Tn + 1) * 2 * Hn * 4);
    unsigned* flags = (unsigned*)alloc(512);                // 128 epoch flags
    float* bfeat  = (float*)alloc((size_t)NTOK * En * 4);
    float* attn   = (float*)alloc((size_t)Bn * Tn * Tn * 4);
    float* mem    = (float*)alloc((size_t)NTOK * Hn * 4);
    float* rl     = (float*)alloc((size_t)NTOK * Gn * 4);
    float* rw     = (float*)alloc((size_t)NTOK * 2 * 4);
    int*   ridx   = (int*)  alloc((size_t)NTOK * 2 * 4);
    float* bgate  = (float*)alloc((size_t)NTOK * Rn * 4);
    float* egb    = (float*)alloc((size_t)NTOK * 4);
    float* bb     = (float*)alloc((size_t)NTOK * Rn * 4);   // mb adjacent (one memset)
    float* mb     = (float*)alloc((size_t)NTOK * Rn * 4);
    float* comb   = (float*)alloc((size_t)NTOK * Rn * 4);
    float* delta  = (float*)alloc((size_t)NTOK * En * 4);
    unsigned short* fbf    = (unsigned short*)alloc((size_t)NTOK * En * 2);
    unsigned short* embbf  = (unsigned short*)alloc((size_t)Vn * En * 2);
    unsigned short* st_bf  = (unsigned short*)alloc((size_t)NTOK * Hn * 2);
    unsigned short* stT_bf = (unsigned short*)alloc((size_t)NTOK * Hn * 2);
    unsigned short* attnbf = (unsigned short*)alloc((size_t)Bn * Tn * Tn * 2);
    unsigned short* Wih_bf = (unsigned short*)alloc((size_t)H3 * En * 2);
    unsigned short* Whf_bf = (unsigned short*)alloc((size_t)4 * En * Hn * 2);
    unsigned short* Whp_bf = (unsigned short*)alloc((size_t)En * 4 * En * 2);
    unsigned short* Wq_bf  = (unsigned short*)alloc((size_t)Mn * Hn * 2);
    unsigned short* Wk_bf  = (unsigned short*)alloc((size_t)Mn * Hn * 2);
    unsigned short* q_bf   = (unsigned short*)alloc((size_t)NTOK * Mn * 2);
    unsigned short* k_bf   = (unsigned short*)alloc((size_t)NTOK * Mn * 2);
    (void)in_sizes; (void)n_in; (void)out_size; (void)ws_size;

    // hseq[0]=0 ; hseq[1..1024]=NaN sentinel ; flags=0 ; basis accumulators=0
    hipMemsetAsync(hseq, 0, (size_t)2 * Hn * 4, stream);
    hipMemsetAsync(hseq + 2 * Hn, 0xFF, (size_t)Tn * 2 * Hn * 4, stream);
    hipMemsetAsync(flags, 0, 512, stream);
    hipMemsetAsync(bb, 0, (size_t)NTOK * Rn * 4 * 2, stream);

    // weight/embedding bf16 conversions
    convbf_k<<<2048, 256, 0, stream>>>(emb, embbf, (long)Vn * En);
    convbf_k<<<512, 256, 0, stream>>>(W_ih, Wih_bf, (long)H3 * En);
    convbf_k<<<512, 256, 0, stream>>>(Whf, Whf_bf, (long)4 * En * Hn);
    convbf_k<<<512, 256, 0, stream>>>(Whp, Whp_bf, (long)En * 4 * En);
    convbf_k<<<128, 256, 0, stream>>>(Wq, Wq_bf, (long)Mn * Hn);
    convbf_k<<<128, 256, 0, stream>>>(Wk, Wk_bf, (long)Mn * Hn);

    // xi = emb[ids] @ W_ih^T + b_ih   (bf16 MFMA, gathered A)
    gemm_bf16_mfma<0, 0><<<dim3(H3 / 128, NTOK / 128, 1), 256, 0, stream>>>(
        embbf, Wih_bf, b_ih, xi, H3, En, 0, 0, 0, ids);
    // GRU scan (flag-published dataflow)
    gru_scan3_k<<<128, 64, 0, stream>>>(xi, W_hh, b_hh, states, hseq, flags);
    // states -> bf16 (row) and bf16 transposed
    convbf_k<<<512, 256, 0, stream>>>(states, st_bf, (long)NTOK * Hn);
    transbf_k<<<dim3(Tn / 32, Hn / 32, Bn), 256, 0, stream>>>(states, stT_bf);
    // head = relu(states @ Whf^T + bhf)^2  -> bf16 (reuses xi buffer)
    gemm_bf16_mfma<2, 1><<<dim3(2048 / 128, NTOK / 128, 1), 256, 0, stream>>>(
        st_bf, Whf_bf, bhf, head_bf, 2048, Hn, 0, 0, 0, nullptr);
    // base_feat = head @ Whp^T + bhp  (f32)
    gemm_bf16_mfma<0, 0><<<dim3(En / 128, NTOK / 128, 1), 256, 0, stream>>>(
        head_bf, Whp_bf, bhp, bfeat, En, 2048, 0, 0, 0, nullptr);
    // router (fp32, tiny)
    gemm_nt_f32<0><<<dim3(1, NTOK / 64), 256, 0, stream>>>(states, Wr, rl, br, NTOK, Gn, Hn);
    route_topk_k<<<NTOK / 256, 256, 0, stream>>>(rl, rw, ridx);
    // q, k (bf16 out)
    gemm_bf16_mfma<0, 1><<<dim3(Mn / 128, NTOK / 128, 1), 256, 0, stream>>>(
        st_bf, Wq_bf, bq, q_bf, Mn, Hn, 0, 0, 0, nullptr);
    gemm_bf16_mfma<0, 1><<<dim3(Mn / 128, NTOK / 128, 1), 256, 0, stream>>>(
        st_bf, Wk_bf, bk, k_bf, Mn, Hn, 0, 0, 0, nullptr);
    // scores = q @ k^T (batched), then causal softmax in-place
    gemm_bf16_mfma<0, 0><<<dim3(Tn / 128, Tn / 128, Bn), 256, 0, stream>>>(
        q_bf, k_bf, nullptr, attn, Tn, Mn, (long)Tn * Mn, (long)Tn * Mn, (long)Tn * Tn, nullptr);
    attn_softmax_k<<<dim3(Tn, Bn), 256, 0, stream>>>(attn);
    convbf_k<<<1024, 256, 0, stream>>>(attn, attnbf, (long)Bn * Tn * Tn);
    // mem_states = attn @ states  (A=attn_bf, B=statesT_bf, batched)
    gemm_bf16_mfma<0, 0><<<dim3(Hn / 128, Tn / 128, Bn), 256, 0, stream>>>(
        attnbf, stT_bf, nullptr, mem, Hn, Tn, (long)Tn * Tn, (long)Hn * Tn, (long)Tn * Hn, nullptr);
    // gates (fp32, tiny)
    gemm_nt_f32<1><<<dim3(1, NTOK / 64), 256, 0, stream>>>(states, Wbg, bgate, bbg, NTOK, Rn, Hn);
    gemm_nt_f32<1><<<dim3(1, NTOK / 64), 256, 0, stream>>>(states, Wg, egb, bg, NTOK, 1, Hn);
    // routed bases (top-2 sparse)
    routed_basis_k<<<dim3(Gn, NTOK / 256), 256, 0, stream>>>(bfeat, base_cw, base_cb, rw, ridx, bb, En);
    routed_basis_k<<<dim3(Gn, NTOK / 256), 256, 0, stream>>>(mem, mem_cw, mem_cb, rw, ridx, mb, Hn);
    // delta = (bb + bs*bgate*mb) @ Wbu^T ; f_total = bf16(base_feat + delta)
    comb_k<<<(NTOK * Rn + 255) / 256, 256, 0, stream>>>(bb, mb, bgate, bsc, comb);
    gemm_nt_f32<0><<<dim3(En / 64, NTOK / 64), 256, 0, stream>>>(comb, Wbu, delta, nullptr, NTOK, En, Rn);
    ftotal_k<<<(NTOK * En + 255) / 256, 256, 0, stream>>>(bfeat, delta, fbf);
    // logits = f_total @ emb^T + out_bias  (both emb matmuls folded into one)
    gemm_bf16_mfma<0, 0><<<dim3(Vn / 128, NTOK / 128, 1), 256, 0, stream>>>(
        fbf, embbf, out_bias, logits, Vn, En, 0, 0, 0, nullptr);
    // copy mechanism scatter
    copy_scatter_k<<<NTOK, 256, 0, stream>>>(logits, attn, egb, ids, esc);
}

// Round 4
// 4835.522 us; speedup vs baseline: 1.6867x; 1.6867x over previous
//
#include <hip/hip_runtime.h>
#include <hip/hip_bf16.h>
#include <stdint.h>

// Problem dims (fixed)
#define Bn   2
#define Tn   1024
#define NTOK 2048      // B*T
#define Vn   32000
#define En   512
#define Hn   768
#define H3   2304      // 3*H
#define Mn   256
#define Rn   64
#define Gn   16

typedef __attribute__((ext_vector_type(8))) short short8;
typedef __attribute__((ext_vector_type(4))) float f32x4;

__device__ __forceinline__ float sigmoidf_(float x) { return 1.f / (1.f + __expf(-x)); }

__device__ __forceinline__ unsigned short f2bf(float x) {
    union { float f; unsigned u; } v; v.f = x;
    unsigned r = v.u + 0x7fffu + ((v.u >> 16) & 1u);   // RNE
    return (unsigned short)(r >> 16);
}

// ---------------------------------------------------------------------------
// fp32 GEMM for small N: C = act(A @ B^T + bias). 64x64 tile, BK=16.
// ACT: 0=none, 1=sigmoid
// ---------------------------------------------------------------------------
template<int ACT>
__global__ __launch_bounds__(256) void gemm_nt_f32(
    const float* __restrict__ A, const float* __restrict__ B,
    float* __restrict__ C, const float* __restrict__ bias,
    int M, int N, int K)
{
    __shared__ float As[16][68];
    __shared__ float Bs[16][68];
    const int m0 = blockIdx.y * 64, n0 = blockIdx.x * 64;
    const int tid = threadIdx.x;
    const int tx = tid & 15, ty = tid >> 4;
    float acc[4][4] = {};
    for (int k0 = 0; k0 < K; k0 += 16) {
        #pragma unroll
        for (int i = 0; i < 4; i++) {
            int idx = tid + i * 256;
            int r = idx >> 4, c = idx & 15;
            int gm = m0 + r;
            As[c][r] = (gm < M) ? A[(long)gm * K + k0 + c] : 0.f;
            int gn = n0 + r;
            Bs[c][r] = (gn < N) ? B[(long)gn * K + k0 + c] : 0.f;
        }
        __syncthreads();
        #pragma unroll
        for (int kk = 0; kk < 16; kk++) {
            float4 a4 = *(const float4*)&As[kk][ty * 4];
            float4 b4 = *(const float4*)&Bs[kk][tx * 4];
            float a[4] = {a4.x, a4.y, a4.z, a4.w};
            float b[4] = {b4.x, b4.y, b4.z, b4.w};
            #pragma unroll
            for (int i = 0; i < 4; i++)
                #pragma unroll
                for (int j = 0; j < 4; j++) acc[i][j] += a[i] * b[j];
        }
        __syncthreads();
    }
    #pragma unroll
    for (int i = 0; i < 4; i++) {
        int gm = m0 + ty * 4 + i; if (gm >= M) continue;
        #pragma unroll
        for (int j = 0; j < 4; j++) {
            int gn = n0 + tx * 4 + j; if (gn >= N) continue;
            float v = acc[i][j] + (bias ? bias[gn] : 0.f);
            if (ACT == 1) v = sigmoidf_(v);
            C[(long)gm * N + gn] = v;
        }
    }
}

// ---------------------------------------------------------------------------
// bf16 MFMA GEMM: C = act(A_bf @ B_bf^T + bias). 128x128 tile, BK=32,
// 4 waves (2x2), 16x16x32 bf16 MFMA, global_load_lds width-16 staging.
// M, N multiples of 128 per launch config; K multiple of 32.
// Optional row-gather on A. Batched via blockIdx.z (element strides).
// ACT: 0=none, 2=relu^2. OBF: 0=f32 out, 1=bf16 out.
// ---------------------------------------------------------------------------
typedef const __attribute__((address_space(1))) void* as1cv_t;
typedef __attribute__((address_space(3))) void* as3v_t;
__device__ __forceinline__ void gload_lds16(const void* g, void* l) {
    __builtin_amdgcn_global_load_lds((as1cv_t)g, (as3v_t)l, 16, 0, 0);
}

template<int ACT, int OBF>
__global__ __launch_bounds__(256) void gemm_bf16_mfma(
    const unsigned short* __restrict__ A, const unsigned short* __restrict__ B,
    const float* __restrict__ bias, void* __restrict__ Cout,
    int N, int K, long sA, long sB, long sC,
    const int* __restrict__ gatherA)
{
    A += blockIdx.z * sA; B += blockIdx.z * sB;
    __shared__ __align__(16) unsigned short As[128 * 32];
    __shared__ __align__(16) unsigned short Bs[128 * 32];
    const int n0 = blockIdx.x * 128;
    const int m0 = blockIdx.y * 128;
    const int tid = threadIdx.x;
    const int lane = tid & 63, wv = tid >> 6;
    const int wr = wv >> 1, wc = wv & 1;
    f32x4 zero4 = {0.f, 0.f, 0.f, 0.f};
    f32x4 acc[4][4];
    #pragma unroll
    for (int i = 0; i < 4; i++)
        #pragma unroll
        for (int j = 0; j < 4; j++) acc[i][j] = zero4;

    const int lrow = lane & 15, lko = (lane >> 4) * 8;
    const int cb = (lane * 16) & 63;          // byte offset within 64B tile row
    int rowsA[2], rowsB[2];
    #pragma unroll
    for (int i = 0; i < 2; i++) {
        int p = i * 4096 + wv * 1024 + lane * 16;
        int row = p >> 6;
        rowsA[i] = gatherA ? gatherA[m0 + row] : (m0 + row);
        rowsB[i] = n0 + row;
    }

    for (int k0 = 0; k0 < K; k0 += 32) {
        __syncthreads();
        #pragma unroll
        for (int i = 0; i < 2; i++) {
            int base = i * 4096 + wv * 1024;  // wave-uniform LDS byte offset
            gload_lds16((const char*)A + ((long)rowsA[i] * K + k0) * 2 + cb, (char*)As + base);
            gload_lds16((const char*)B + ((long)rowsB[i] * K + k0) * 2 + cb, (char*)Bs + base);
        }
        __syncthreads();
        short8 af[4], bfr[4];
        #pragma unroll
        for (int m = 0; m < 4; m++)
            af[m] = *(const short8*)((const char*)As + (wr * 64 + m * 16 + lrow) * 64 + lko * 2);
        #pragma unroll
        for (int n = 0; n < 4; n++)
            bfr[n] = *(const short8*)((const char*)Bs + (wc * 64 + n * 16 + lrow) * 64 + lko * 2);
        #pragma unroll
        for (int m = 0; m < 4; m++)
            #pragma unroll
            for (int n = 0; n < 4; n++)
                acc[m][n] = __builtin_amdgcn_mfma_f32_16x16x32_bf16(af[m], bfr[n], acc[m][n], 0, 0, 0);
    }
    const int orow = (lane >> 4) * 4, ocol = lane & 15;
    float* Cf = (float*)Cout + blockIdx.z * sC;
    unsigned short* Cb = (unsigned short*)Cout + blockIdx.z * sC;
    #pragma unroll
    for (int m = 0; m < 4; m++) {
        #pragma unroll
        for (int n = 0; n < 4; n++) {
            int col = n0 + wc * 64 + n * 16 + ocol;
            float bv = bias ? bias[col] : 0.f;
            int rbase = m0 + wr * 64 + m * 16 + orow;
            #pragma unroll
            for (int r2 = 0; r2 < 4; r2++) {
                float v = acc[m][n][r2] + bv;
                if (ACT == 2) { v = fmaxf(v, 0.f); v = v * v; }
                if (OBF) Cb[(long)(rbase + r2) * N + col] = f2bf(v);
                else     Cf[(long)(rbase + r2) * N + col] = v;
            }
        }
    }
}

// ---------------------------------------------------------------------------
// GRU scan v2 (proven): barrier-free dataflow, direct data poll on NaN
// sentinel. 128 blocks x 64 threads (1 wave each). Wave w owns j in [6w,6w+6).
// Poll uses b64 loads (12/lane/iter) to halve IC poll traffic vs v2's 24xb32.
// ---------------------------------------------------------------------------
#define GRU_SENT 0xFFFFFFFFu
__global__ __launch_bounds__(64, 1) void gru_scan2_k(
    const float* __restrict__ xi, const float* __restrict__ Whh,
    const float* __restrict__ bhh, float* __restrict__ states,
    float* __restrict__ hseq)
{
    const int w = blockIdx.x;        // 0..127
    const int lane = threadIdx.x;    // 0..63
    const int jb = w * 6;

    float wreg[3][6][12];
    #pragma unroll
    for (int g = 0; g < 3; g++)
        #pragma unroll
        for (int jo = 0; jo < 6; jo++) {
            const float* wp = Whh + (long)(g * Hn + jb + jo) * Hn + lane * 12;
            #pragma unroll
            for (int c = 0; c < 12; c += 4) {
                float4 v = *(const float4*)(wp + c);
                wreg[g][jo][c + 0] = v.x; wreg[g][jo][c + 1] = v.y;
                wreg[g][jo][c + 2] = v.z; wreg[g][jo][c + 3] = v.w;
            }
        }

    const bool own = (lane < 12);
    const int jo_own = lane >> 1, b_own = lane & 1;
    const int j_own = jb + jo_own;
    float bh0 = 0.f, bh1 = 0.f, bh2 = 0.f;
    if (own) { bh0 = bhh[j_own]; bh1 = bhh[Hn + j_own]; bh2 = bhh[2 * Hn + j_own]; }
    float hreg = 0.f;   // owner's exact fp32 h

    const uint* __restrict__ hsq = (const uint*)hseq;
    uint* __restrict__ hsqw = (uint*)hseq;

    for (int t = 0; t < Tn; t++) {
        // xi prefetch (independent of h availability; overlaps the poll)
        float xg0 = 0.f, xg1 = 0.f, xg2 = 0.f;
        if (own) {
            const float* xp = xi + ((long)b_own * Tn + t) * H3 + j_own;
            xg0 = xp[0]; xg1 = xp[Hn]; xg2 = xp[2 * Hn];
        }

        // poll this lane's 24 h dwords for step t (12 x b64 loads)
        const uint* hp = hsq + (long)t * 2 * Hn + lane * 12;
        uint hu[24];
        bool ready;
        do {
            #pragma unroll
            for (int b = 0; b < 2; b++)
                #pragma unroll
                for (int c3 = 0; c3 < 6; c3++) {
                    unsigned long long u8 = __hip_atomic_load(
                        (const unsigned long long*)(hp + b * Hn) + c3,
                        __ATOMIC_RELAXED, __HIP_MEMORY_SCOPE_AGENT);
                    hu[b * 12 + c3 * 2]     = (unsigned)u8;
                    hu[b * 12 + c3 * 2 + 1] = (unsigned)(u8 >> 32);
                }
            ready = true;
            #pragma unroll
            for (int i = 0; i < 24; i++) ready = ready && (hu[i] != GRU_SENT);
        } while (!ready);
        float hv[2][12];
        #pragma unroll
        for (int b = 0; b < 2; b++)
            #pragma unroll
            for (int c = 0; c < 12; c++) hv[b][c] = __uint_as_float(hu[b * 12 + c]);

        // dot products: 18 rows x 2 batches
        float acc[3][6][2];
        #pragma unroll
        for (int g = 0; g < 3; g++)
            #pragma unroll
            for (int jo = 0; jo < 6; jo++) {
                float s0 = 0.f, s1 = 0.f;
                #pragma unroll
                for (int c = 0; c < 12; c++) {
                    s0 += wreg[g][jo][c] * hv[0][c];
                    s1 += wreg[g][jo][c] * hv[1][c];
                }
                acc[g][jo][0] = s0; acc[g][jo][1] = s1;
            }

        // batch-folded butterfly: after level-1, lane parity selects batch
        float red[3][6];
        #pragma unroll
        for (int g = 0; g < 3; g++)
            #pragma unroll
            for (int jo = 0; jo < 6; jo++) {
                float keep = (lane & 1) ? acc[g][jo][1] : acc[g][jo][0];
                float send = (lane & 1) ? acc[g][jo][0] : acc[g][jo][1];
                red[g][jo] = keep + __shfl_xor(send, 1, 64);
            }
        #pragma unroll
        for (int m = 2; m < 64; m <<= 1)
            #pragma unroll
            for (int g = 0; g < 3; g++)
                #pragma unroll
                for (int jo = 0; jo < 6; jo++)
                    red[g][jo] += __shfl_xor(red[g][jo], m, 64);

        if (own) {
            float hr = 0.f, hz = 0.f, hn = 0.f;
            #pragma unroll
            for (int jo = 0; jo < 6; jo++)
                if (jo_own == jo) { hr = red[0][jo]; hz = red[1][jo]; hn = red[2][jo]; }
            hr += bh0; hz += bh1; hn += bh2;
            float rr = sigmoidf_(xg0 + hr);
            float zz = sigmoidf_(xg1 + hz);
            float nn = tanhf(xg2 + rr * hn);
            float hnew = (1.f - zz) * nn + zz * hreg;
            hreg = hnew;
            __hip_atomic_store(hsqw + (long)(t + 1) * 2 * Hn + b_own * Hn + j_own,
                               __float_as_uint(hnew),
                               __ATOMIC_RELAXED, __HIP_MEMORY_SCOPE_AGENT);
            states[((long)b_own * Tn + t) * Hn + j_own] = hnew;
        }
    }
}

// ---------------------------------------------------------------------------
// Attention softmax (strictly causal, in-place over scores) + bf16 copy out.
// ---------------------------------------------------------------------------
__global__ __launch_bounds__(256) void attn_softmax_k(float* __restrict__ attn,
                                                      unsigned short* __restrict__ attnbf)
{
    const int t = blockIdx.x, b = blockIdx.y;
    float* row = attn + ((long)b * Tn + t) * Tn;
    unsigned short* brow = attnbf + ((long)b * Tn + t) * Tn;
    const int tid = threadIdx.x;
    __shared__ float red[256];
    const float scale = 0.0625f;  // 1/sqrt(256)
    float mx = -3.4e38f;
    for (int s = tid; s < t; s += 256) mx = fmaxf(mx, row[s] * scale);
    red[tid] = mx; __syncthreads();
    for (int st = 128; st > 0; st >>= 1) { if (tid < st) red[tid] = fmaxf(red[tid], red[tid + st]); __syncthreads(); }
    mx = red[0]; __syncthreads();
    float sum = 0.f;
    for (int s = tid; s < t; s += 256) { float e = __expf(row[s] * scale - mx); row[s] = e; sum += e; }
    red[tid] = sum; __syncthreads();
    for (int st = 128; st > 0; st >>= 1) { if (tid < st) red[tid] += red[tid + st]; __syncthreads(); }
    sum = red[0];
    float inv = 1.f / fmaxf(sum, 1e-6f);
    for (int s = tid; s < t; s += 256) { float v = row[s] * inv; row[s] = v; brow[s] = f2bf(v); }
    for (int s = t + tid; s < Tn; s += 256) { row[s] = 0.f; brow[s] = 0; }
}

// top-2 of 16 router logits + 2-way softmax (tie -> lowest index, matches top_k)
__global__ void route_topk_k(const float* __restrict__ rl, float* __restrict__ rw, int* __restrict__ ridx)
{
    int n = blockIdx.x * blockDim.x + threadIdx.x;
    if (n >= NTOK) return;
    const float* r = rl + (long)n * Gn;
    float v1 = -3.4e38f; int i1 = 0;
    #pragma unroll
    for (int g = 0; g < Gn; g++) { float v = r[g]; if (v > v1) { v1 = v; i1 = g; } }
    float v2 = -3.4e38f; int i2 = 0;
    #pragma unroll
    for (int g = 0; g < Gn; g++) { if (g == i1) continue; float v = r[g]; if (v > v2) { v2 = v; i2 = g; } }
    float e2 = __expf(v2 - v1);
    float s = 1.f + e2;
    rw[n * 2] = 1.f / s; rw[n * 2 + 1] = e2 / s;
    ridx[n * 2] = i1; ridx[n * 2 + 1] = i2;
}

// cw (G,D,R) f32 -> cwT (G,R,D) bf16 tiled transpose. grid (G, D/32), 256 thr.
__global__ __launch_bounds__(256) void cwtrans_k(const float* __restrict__ cw,
                                                 unsigned short* __restrict__ cwT, int D)
{
    const int g = blockIdx.x, d0 = blockIdx.y * 32;
    __shared__ float tile[32][65];
    #pragma unroll
    for (int i = 0; i < 8; i++) {
        int idx = threadIdx.x + i * 256;
        int dr = idx >> 6, rc = idx & 63;
        tile[dr][rc] = cw[((long)g * D + d0 + dr) * Rn + rc];
    }
    __syncthreads();
    #pragma unroll
    for (int i = 0; i < 8; i++) {
        int idx = threadIdx.x + i * 256;
        int rr = idx >> 5, dc = idx & 31;
        cwT[((long)g * Rn + rr) * D + d0 + dc] = f2bf(tile[dc][rr]);
    }
}

// comb = bf16( top2(projB) + bs * bgate * top2(projM) ), per (n, r)
__global__ __launch_bounds__(256) void comb2_k(
    const float* __restrict__ projB, const float* __restrict__ projM,
    const float* __restrict__ rw, const int* __restrict__ ridx,
    const float* __restrict__ bgate, const float* __restrict__ bs_ptr,
    unsigned short* __restrict__ comb_bf)
{
    const int n = blockIdx.x * 4 + (threadIdx.x >> 6);
    const int r = threadIdx.x & 63;
    float w0 = rw[n * 2], w1 = rw[n * 2 + 1];
    int g0 = ridx[n * 2] * 64, g1 = ridx[n * 2 + 1] * 64;
    const float* pb = projB + (long)n * (Gn * Rn);
    const float* pm = projM + (long)n * (Gn * Rn);
    float vb = w0 * pb[g0 + r] + w1 * pb[g1 + r];
    float vm = w0 * pm[g0 + r] + w1 * pm[g1 + r];
    comb_bf[(long)n * Rn + r] = f2bf(vb + bs_ptr[0] * bgate[(long)n * Rn + r] * vm);
}

__global__ void ftotal_k(const float* __restrict__ bf, const float* __restrict__ dl,
                         unsigned short* __restrict__ outb)
{
    int i = blockIdx.x * 256 + threadIdx.x;
    if (i < NTOK * En) outb[i] = f2bf(bf[i] + dl[i]);
}

// generic f32 -> bf16 convert (n multiple of 4)
__global__ void convbf_k(const float* __restrict__ in, unsigned short* __restrict__ outb, long n)
{
    long i = (long)(blockIdx.x * 256 + threadIdx.x) * 4;
    for (; i < n; i += (long)gridDim.x * 256 * 4) {
        float4 v = *(const float4*)(in + i);
        ushort4 u;
        u.x = f2bf(v.x); u.y = f2bf(v.y); u.z = f2bf(v.z); u.w = f2bf(v.w);
        *(ushort4*)(outb + i) = u;
    }
}

// states (2,1024,768) f32 -> statesT (2,768,1024) bf16, tiled transpose
__global__ __launch_bounds__(256) void transbf_k(const float* __restrict__ st,
                                                 unsigned short* __restrict__ stT)
{
    __shared__ float tile[32][33];
    const int b = blockIdx.z;
    const int t0 = blockIdx.x * 32, h0 = blockIdx.y * 32;
    const int tx = threadIdx.x & 31, ty = threadIdx.x >> 5;   // 32x8
    #pragma unroll
    for (int r = ty; r < 32; r += 8)
        tile[r][tx] = st[((long)b * Tn + t0 + r) * Hn + h0 + tx];
    __syncthreads();
    #pragma unroll
    for (int r = ty; r < 32; r += 8)
        stT[((long)b * Hn + h0 + r) * Tn + t0 + tx] = f2bf(tile[tx][r]);
}

// copy mechanism: logits[b,t, ids[b,s]] += attn[b,t,s] * eg[b,t] * exact_scale
__global__ __launch_bounds__(256) void copy_scatter_k(
    float* __restrict__ logits, const float* __restrict__ attn,
    const float* __restrict__ eg, const int* __restrict__ ids,
    const float* __restrict__ esc)
{
    const int n = blockIdx.x;
    const int b = n >> 10, t = n & 1023;
    const float g = eg[n] * esc[0];
    const float* arow = attn + ((long)b * Tn + t) * Tn;
    float* lrow = logits + (long)n * Vn;
    const int* idrow = ids + b * Tn;
    for (int s = threadIdx.x; s < t; s += 256) {
        float a = arow[s];
        atomicAdd(lrow + idrow[s], a * g);
    }
}

// ---------------------------------------------------------------------------
extern "C" void kernel_launch(void* const* d_in, const int* in_sizes, int n_in,
                              void* d_out, int out_size, void* d_ws, size_t ws_size,
                              hipStream_t stream)
{
    const int*   ids      = (const int*)  d_in[0];
    const float* emb      = (const float*)d_in[1];
    const float* W_ih     = (const float*)d_in[2];
    const float* W_hh     = (const float*)d_in[3];
    const float* b_ih     = (const float*)d_in[4];
    const float* b_hh     = (const float*)d_in[5];
    const float* Wq       = (const float*)d_in[6];
    const float* bq       = (const float*)d_in[7];
    const float* Wk       = (const float*)d_in[8];
    const float* bk       = (const float*)d_in[9];
    const float* Wg       = (const float*)d_in[10];
    const float* bg       = (const float*)d_in[11];
    const float* Whf      = (const float*)d_in[12];
    const float* bhf      = (const float*)d_in[13];
    const float* Whp      = (const float*)d_in[14];
    const float* bhp      = (const float*)d_in[15];
    const float* Wr       = (const float*)d_in[16];
    const float* br       = (const float*)d_in[17];
    const float* base_cw  = (const float*)d_in[18];
    const float* base_cb  = (const float*)d_in[19];
    const float* mem_cw   = (const float*)d_in[20];
    const float* mem_cb   = (const float*)d_in[21];
    const float* Wbg      = (const float*)d_in[22];
    const float* bbg      = (const float*)d_in[23];
    const float* Wbu      = (const float*)d_in[24];
    const float* out_bias = (const float*)d_in[25];
    const float* esc      = (const float*)d_in[26];
    const float* bsc      = (const float*)d_in[27];
    float* logits = (float*)d_out;

    char* ws = (char*)d_ws;
    size_t off = 0;
    auto alloc = [&](size_t bytes) -> void* {
        void* p = ws + off; off = (off + bytes + 255) & ~(size_t)255; return p;
    };
    float* xi     = (float*)alloc((size_t)NTOK * H3 * 4);   // reused as head_bf after GRU
    unsigned short* head_bf = (unsigned short*)xi;          // 2048*2048*2B <= 2048*2304*4B
    float* states = (float*)alloc((size_t)NTOK * Hn * 4);
    float* hseq   = (float*)alloc((size_t)(Tn + 1) * 2 * Hn * 4);
    float* bfeat  = (float*)alloc((size_t)NTOK * En * 4);
    float* attn   = (float*)alloc((size_t)Bn * Tn * Tn * 4);
    float* rl     = (float*)alloc((size_t)NTOK * Gn * 4);
    float* rw     = (float*)alloc((size_t)NTOK * 2 * 4);
    int*   ridx   = (int*)  alloc((size_t)NTOK * 2 * 4);
    float* bgate  = (float*)alloc((size_t)NTOK * Rn * 4);
    float* egb    = (float*)alloc((size_t)NTOK * 4);
    float* projB  = (float*)alloc((size_t)NTOK * Gn * Rn * 4);
    float* projM  = (float*)alloc((size_t)NTOK * Gn * Rn * 4);
    float* delta  = (float*)alloc((size_t)NTOK * En * 4);
    unsigned short* comb_bf = (unsigned short*)alloc((size_t)NTOK * Rn * 2);
    unsigned short* fbf    = (unsigned short*)alloc((size_t)NTOK * En * 2);
    unsigned short* embbf  = (unsigned short*)alloc((size_t)Vn * En * 2);
    unsigned short* st_bf  = (unsigned short*)alloc((size_t)NTOK * Hn * 2);
    unsigned short* stT_bf = (unsigned short*)alloc((size_t)NTOK * Hn * 2);
    unsigned short* attnbf = (unsigned short*)alloc((size_t)Bn * Tn * Tn * 2);
    unsigned short* bfeat_bf = (unsigned short*)alloc((size_t)NTOK * En * 2);
    unsigned short* mem_bf = (unsigned short*)alloc((size_t)NTOK * Hn * 2);
    unsigned short* Wih_bf = (unsigned short*)alloc((size_t)H3 * En * 2);
    unsigned short* Whf_bf = (unsigned short*)alloc((size_t)4 * En * Hn * 2);
    unsigned short* Whp_bf = (unsigned short*)alloc((size_t)En * 4 * En * 2);
    unsigned short* Wq_bf  = (unsigned short*)alloc((size_t)Mn * Hn * 2);
    unsigned short* Wk_bf  = (unsigned short*)alloc((size_t)Mn * Hn * 2);
    unsigned short* Wbu_bf = (unsigned short*)alloc((size_t)En * Rn * 2);
    unsigned short* cwTb   = (unsigned short*)alloc((size_t)Gn * Rn * En * 2);
    unsigned short* cwTm   = (unsigned short*)alloc((size_t)Gn * Rn * Hn * 2);
    unsigned short* q_bf   = (unsigned short*)alloc((size_t)NTOK * Mn * 2);
    unsigned short* k_bf   = (unsigned short*)alloc((size_t)NTOK * Mn * 2);
    (void)in_sizes; (void)n_in; (void)out_size; (void)ws_size;

    // hseq[0]=0 ; hseq[1..1024]=NaN sentinel
    hipMemsetAsync(hseq, 0, (size_t)2 * Hn * 4, stream);
    hipMemsetAsync(hseq + 2 * Hn, 0xFF, (size_t)Tn * 2 * Hn * 4, stream);

    // weight/embedding bf16 conversions
    convbf_k<<<2048, 256, 0, stream>>>(emb, embbf, (long)Vn * En);
    convbf_k<<<512, 256, 0, stream>>>(W_ih, Wih_bf, (long)H3 * En);
    convbf_k<<<512, 256, 0, stream>>>(Whf, Whf_bf, (long)4 * En * Hn);
    convbf_k<<<512, 256, 0, stream>>>(Whp, Whp_bf, (long)En * 4 * En);
    convbf_k<<<128, 256, 0, stream>>>(Wq, Wq_bf, (long)Mn * Hn);
    convbf_k<<<128, 256, 0, stream>>>(Wk, Wk_bf, (long)Mn * Hn);
    convbf_k<<<32, 256, 0, stream>>>(Wbu, Wbu_bf, (long)En * Rn);
    cwtrans_k<<<dim3(Gn, En / 32), 256, 0, stream>>>(base_cw, cwTb, En);
    cwtrans_k<<<dim3(Gn, Hn / 32), 256, 0, stream>>>(mem_cw, cwTm, Hn);

    // xi = emb[ids] @ W_ih^T + b_ih   (bf16 MFMA, gathered A)
    gemm_bf16_mfma<0, 0><<<dim3(H3 / 128, NTOK / 128, 1), 256, 0, stream>>>(
        embbf, Wih_bf, b_ih, xi, H3, En, 0, 0, 0, ids);
    // GRU scan (data-poll dataflow)
    gru_scan2_k<<<128, 64, 0, stream>>>(xi, W_hh, b_hh, states, hseq);
    // states -> bf16 (row) and bf16 transposed
    convbf_k<<<512, 256, 0, stream>>>(states, st_bf, (long)NTOK * Hn);
    transbf_k<<<dim3(Tn / 32, Hn / 32, Bn), 256, 0, stream>>>(states, stT_bf);
    // head = relu(states @ Whf^T + bhf)^2  -> bf16 (reuses xi buffer)
    gemm_bf16_mfma<2, 1><<<dim3(2048 / 128, NTOK / 128, 1), 256, 0, stream>>>(
        st_bf, Whf_bf, bhf, head_bf, 2048, Hn, 0, 0, 0, nullptr);
    // base_feat = head @ Whp^T + bhp  (f32) ; + bf16 copy
    gemm_bf16_mfma<0, 0><<<dim3(En / 128, NTOK / 128, 1), 256, 0, stream>>>(
        head_bf, Whp_bf, bhp, bfeat, En, 2048, 0, 0, 0, nullptr);
    convbf_k<<<256, 256, 0, stream>>>(bfeat, bfeat_bf, (long)NTOK * En);
    // router (fp32, tiny)
    gemm_nt_f32<0><<<dim3(1, NTOK / 64), 256, 0, stream>>>(states, Wr, rl, br, NTOK, Gn, Hn);
    route_topk_k<<<NTOK / 256, 256, 0, stream>>>(rl, rw, ridx);
    // q, k (bf16 out)
    gemm_bf16_mfma<0, 1><<<dim3(Mn / 128, NTOK / 128, 1), 256, 0, stream>>>(
        st_bf, Wq_bf, bq, q_bf, Mn, Hn, 0, 0, 0, nullptr);
    gemm_bf16_mfma<0, 1><<<dim3(Mn / 128, NTOK / 128, 1), 256, 0, stream>>>(
        st_bf, Wk_bf, bk, k_bf, Mn, Hn, 0, 0, 0, nullptr);
    // scores = q @ k^T (batched), causal softmax in-place (+ bf16 out)
    gemm_bf16_mfma<0, 0><<<dim3(Tn / 128, Tn / 128, Bn), 256, 0, stream>>>(
        q_bf, k_bf, nullptr, attn, Tn, Mn, (long)Tn * Mn, (long)Tn * Mn, (long)Tn * Tn, nullptr);
    attn_softmax_k<<<dim3(Tn, Bn), 256, 0, stream>>>(attn, attnbf);
    // mem_states = attn @ states  (A=attn_bf, B=statesT_bf, batched) -> bf16
    gemm_bf16_mfma<0, 1><<<dim3(Hn / 128, Tn / 128, Bn), 256, 0, stream>>>(
        attnbf, stT_bf, nullptr, mem_bf, Hn, Tn, (long)Tn * Tn, (long)Hn * Tn, (long)Tn * Hn, nullptr);
    // gates (fp32, tiny)
    gemm_nt_f32<1><<<dim3(1, NTOK / 64), 256, 0, stream>>>(states, Wbg, bgate, bbg, NTOK, Rn, Hn);
    gemm_nt_f32<1><<<dim3(1, NTOK / 64), 256, 0, stream>>>(states, Wg, egb, bg, NTOK, 1, Hn);
    // dense routed projections: proj = inp @ cwT^T + cb   (N = G*R = 1024)
    gemm_bf16_mfma<0, 0><<<dim3(Gn * Rn / 128, NTOK / 128, 1), 256, 0, stream>>>(
        bfeat_bf, cwTb, base_cb, projB, Gn * Rn, En, 0, 0, 0, nullptr);
    gemm_bf16_mfma<0, 0><<<dim3(Gn * Rn / 128, NTOK / 128, 1), 256, 0, stream>>>(
        mem_bf, cwTm, mem_cb, projM, Gn * Rn, Hn, 0, 0, 0, nullptr);
    // top-2 gather + gate combine -> comb (bf16)
    comb2_k<<<NTOK / 4, 256, 0, stream>>>(projB, projM, rw, ridx, bgate, bsc, comb_bf);
    // delta = comb @ Wbu^T  (bf16 MFMA, K=64)
    gemm_bf16_mfma<0, 0><<<dim3(En / 128, NTOK / 128, 1), 256, 0, stream>>>(
        comb_bf, Wbu_bf, nullptr, delta, En, Rn, 0, 0, 0, nullptr);
    // f_total = bf16(base_feat + delta)
    ftotal_k<<<(NTOK * En + 255) / 256, 256, 0, stream>>>(bfeat, delta, fbf);
    // logits = f_total @ emb^T + out_bias  (both emb matmuls folded into one)
    gemm_bf16_mfma<0, 0><<<dim3(Vn / 128, NTOK / 128, 1), 256, 0, stream>>>(
        fbf, embbf, out_bias, logits, Vn, En, 0, 0, 0, nullptr);
    // copy mechanism scatter
    copy_scatter_k<<<NTOK, 256, 0, stream>>>(logits, attn, egb, ids, esc);
}